// Round 7
// baseline (581.295 us; speedup 1.0000x reference)
//
#include <hip/hip_runtime.h>
#include <math.h>
#include <utility>

// ============================================================================
// EnhancedGrayscaleCombinedLoss: 0.3 * L2 + 0.7 * (1 - MS-SSIM(3 scales))
// B=64, C=1, H=176, W=1008 fp32. Out: [total, l2, ssim_loss].
// scale0: win 11x15 pad(5,7) out 176x1008 ; scale1: 9x12 pad(4,6) out 88x505 ;
// scale2: 7x10 pad(3,5) out 44x253. Window separable: outer(gh, gw).
//
// R5 (2nd resubmit after infra failures): R4 structure with the scratch bug
// fixed. h-pass: 20-tap window in 10 named ext_vector(4) registers; tap loop
// is template<int P>+if constexpr (all extracts/inserts literal-indexed ->
// registers by construction). Boundary: clamped-address loads + selects
// (no arrays). Phase 2 = R2's proven conflict-free scalar-LDS sliding v-pass.
// ============================================================================

constexpr int NPOOL = 1024;
constexpr int NS0 = 11264;   // 16 x 11 x 64 ssim0 tiles
constexpr int NS1 = 3072;    //  8 x  6 x 64
constexpr int NS2 = 768;     //  4 x  3 x 64

typedef float f4v __attribute__((ext_vector_type(4)));

static __device__ __forceinline__ double wred(double v) {
#pragma unroll
    for (int off = 32; off > 0; off >>= 1) v += __shfl_down(v, off, 64);
    return v;
}
static __device__ __forceinline__ float readlane_f(float v, int l) {
    return __int_as_float(__builtin_amdgcn_readlane(__float_as_int(v), l));
}
static __device__ __forceinline__ float firstlane_f(float v) {
    return __int_as_float(__builtin_amdgcn_readfirstlane(__float_as_int(v)));
}

// Normalized 1D gaussian, cooperatively computed, landed in SGPRs.
template <int K>
static __device__ __forceinline__ void gauss_uni(float sigma, float (&g)[K]) {
    const int lane = threadIdx.x & 63;
    const int d = lane - K / 2;
    const float inv2s2 = 1.0f / (2.0f * sigma * sigma);
    float e = (lane < K) ? __expf(-(float)(d * d) * inv2s2) : 0.0f;
    float s = e;
#pragma unroll
    for (int off = 8; off > 0; off >>= 1) s += __shfl_down(s, off, 16);
    const float inv = 1.0f / __shfl(s, 0, 64);
#pragma unroll
    for (int k = 0; k < K; ++k) g[k] = firstlane_f(readlane_f(e, k) * inv);
}

// ---- compile-time element extract from 5 named f4v registers ----------------
template <int I>
static __device__ __forceinline__ float vel(const f4v& a0, const f4v& a1,
                                            const f4v& a2, const f4v& a3,
                                            const f4v& a4) {
    if constexpr (I < 4)       return a0[I];
    else if constexpr (I < 8)  return a1[I - 4];
    else if constexpr (I < 12) return a2[I - 8];
    else if constexpr (I < 16) return a3[I - 12];
    else                       return a4[I - 16];
}

// ---- one tap position P: contribute to the 4 output points ------------------
template <int KW, int OFFW, int P>
static __device__ __forceinline__ void tap1(
    const f4v& xa0, const f4v& xa1, const f4v& xa2, const f4v& xa3, const f4v& xa4,
    const f4v& ya0, const f4v& ya1, const f4v& ya2, const f4v& ya3, const f4v& ya4,
    const float (&gw)[KW],
    f4v& omx, f4v& omy, f4v& oxx, f4v& oyy, f4v& oxy)
{
    if constexpr ((P - OFFW) >= 0 && (P - OFFW - 3) < KW) {
        const float xe = vel<P>(xa0, xa1, xa2, xa3, xa4);
        const float ye = vel<P>(ya0, ya1, ya2, ya3, ya4);
#define TAPJ(J)                                                         \
        { constexpr int K_ = P - OFFW - (J);                            \
          if constexpr (K_ >= 0 && K_ < KW) {                           \
            const float gx = gw[K_] * xe;                               \
            const float gy = gw[K_] * ye;                               \
            omx[J] += gx; omy[J] += gy;                                 \
            oxx[J] = fmaf(gx, xe, oxx[J]);                              \
            oyy[J] = fmaf(gy, ye, oyy[J]);                              \
            oxy[J] = fmaf(gx, ye, oxy[J]);                              \
          } }
        TAPJ(0) TAPJ(1) TAPJ(2) TAPJ(3)
#undef TAPJ
    }
}

template <int KW, int OFFW, int... Ps>
static __device__ __forceinline__ void tap_all(
    std::integer_sequence<int, Ps...>,
    const f4v& xa0, const f4v& xa1, const f4v& xa2, const f4v& xa3, const f4v& xa4,
    const f4v& ya0, const f4v& ya1, const f4v& ya2, const f4v& ya3, const f4v& ya4,
    const float (&gw)[KW],
    f4v& omx, f4v& omy, f4v& oxx, f4v& oyy, f4v& oxy)
{
    (tap1<KW, OFFW, Ps>(xa0, xa1, xa2, xa3, xa4, ya0, ya1, ya2, ya3, ya4,
                        gw, omx, omy, oxx, oyy, oxy), ...);
}

// ---------------- fused separable SSIM, one 16x64 output tile ----------------
// NEED_L=false: accumulate cs ; NEED_L=true: accumulate l*cs. One slot/block.

template <int KH, int KW, int H, int W, int Wout, bool NEED_L>
static __device__ void ssim_scale(const float* __restrict__ X,
                                  const float* __restrict__ Y,
                                  int bx, int by, int bz,
                                  float* __restrict__ pl,
                                  double* __restrict__ red,
                                  double* __restrict__ slot)
{
    constexpr int TH = 16, TW = 64;
    constexpr int PADH = KH / 2, PADW = KW / 2;
    constexpr int RH = TH + KH - 1;          // h-rows needed
    constexpr int PS = RH * TW;              // plane stride (floats)
    constexpr int OFFW = 8 - PADW;           // first tap offset in the 20-vec

    const int tid = threadIdx.x;
    const int i0 = by * TH, j0 = bx * TW;
    const float* Xb = X + (size_t)bz * H * W;
    const float* Yb = Y + (size_t)bz * H * W;

    float gh[KH], gw[KW];
    gauss_uni<KH>(1.5f, gh);
    gauss_uni<KW>(1.5f * (float)KW / (float)KH, gw);

    // ---- phase 1: horizontal conv of 5 maps, 4 h-points per task -----------
    for (int t = tid; t < RH * 16; t += 256) {
        const int r  = t >> 4;
        const int cg = t & 15;
        const int gi = i0 + r - PADH;
        const int ac = j0 + 4 * cg - 8;      // 16B-aligned load base
        const bool rowok = (unsigned)gi < (unsigned)H;

        f4v xa0, xa1, xa2, xa3, xa4, ya0, ya1, ya2, ya3, ya4;
        if (rowok && ac >= 0 && ac + 20 <= W) {
            const float* xr = Xb + (size_t)gi * W + ac;
            const float* yr = Yb + (size_t)gi * W + ac;
            xa0 = *(const f4v*)(xr);      ya0 = *(const f4v*)(yr);
            xa1 = *(const f4v*)(xr + 4);  ya1 = *(const f4v*)(yr + 4);
            xa2 = *(const f4v*)(xr + 8);  ya2 = *(const f4v*)(yr + 8);
            xa3 = *(const f4v*)(xr + 12); ya3 = *(const f4v*)(yr + 12);
            xa4 = *(const f4v*)(xr + 16); ya4 = *(const f4v*)(yr + 16);
        } else {
            const int gic = min(max(gi, 0), H - 1);
            const float* xr = Xb + (size_t)gic * W;
            const float* yr = Yb + (size_t)gic * W;
#define LQ(i, cmp, idx)                                                  \
            { const int col  = ac + (idx);                               \
              const bool ok  = rowok && ((unsigned)col < (unsigned)W);   \
              const int colc = min(max(col, 0), W - 1);                  \
              xa##i.cmp = ok ? xr[colc] : 0.f;                           \
              ya##i.cmp = ok ? yr[colc] : 0.f; }
            LQ(0, x, 0)  LQ(0, y, 1)  LQ(0, z, 2)  LQ(0, w, 3)
            LQ(1, x, 4)  LQ(1, y, 5)  LQ(1, z, 6)  LQ(1, w, 7)
            LQ(2, x, 8)  LQ(2, y, 9)  LQ(2, z, 10) LQ(2, w, 11)
            LQ(3, x, 12) LQ(3, y, 13) LQ(3, z, 14) LQ(3, w, 15)
            LQ(4, x, 16) LQ(4, y, 17) LQ(4, z, 18) LQ(4, w, 19)
#undef LQ
        }

        f4v omx = {0.f, 0.f, 0.f, 0.f};
        f4v omy = {0.f, 0.f, 0.f, 0.f};
        f4v oxx = {0.f, 0.f, 0.f, 0.f};
        f4v oyy = {0.f, 0.f, 0.f, 0.f};
        f4v oxy = {0.f, 0.f, 0.f, 0.f};
        tap_all<KW, OFFW>(std::make_integer_sequence<int, 20>{},
                          xa0, xa1, xa2, xa3, xa4, ya0, ya1, ya2, ya3, ya4,
                          gw, omx, omy, oxx, oyy, oxy);

        float* base = pl + r * TW + 4 * cg;
        *(f4v*)(base + 0 * PS) = omx;
        *(f4v*)(base + 1 * PS) = omy;
        *(f4v*)(base + 2 * PS) = oxx;
        *(f4v*)(base + 3 * PS) = oyy;
        *(f4v*)(base + 4 * PS) = oxy;
    }
    __syncthreads();

    // ---- phase 2: vertical conv (4 rows/thread, sliding) + SSIM ------------
    const int c  = tid & 63;
    const int rg = tid >> 6;
    float acc[4][5];
#pragma unroll
    for (int r = 0; r < 4; ++r)
#pragma unroll
        for (int m = 0; m < 5; ++m) acc[r][m] = 0.f;

    const float* plc = pl + 4 * rg * TW + c;
#pragma unroll
    for (int j = 0; j < KH + 3; ++j) {
        float hv[5];
#pragma unroll
        for (int m = 0; m < 5; ++m) hv[m] = plc[m * PS + j * TW];
#pragma unroll
        for (int r = 0; r < 4; ++r) {
            const int kk = j - r;
            if (kk >= 0 && kk < KH) {
#pragma unroll
                for (int m = 0; m < 5; ++m)
                    acc[r][m] = fmaf(gh[kk], hv[m], acc[r][m]);
            }
        }
    }

    float sum_f = 0.f;
    const int gj  = j0 + c;
    const int gi0 = i0 + 4 * rg;
#pragma unroll
    for (int r = 0; r < 4; ++r) {
        if (gi0 + r < H && gj < Wout) {
            const float mxv = acc[r][0], myv = acc[r][1];
            const float mx2 = mxv * mxv, my2 = myv * myv, mxy = mxv * myv;
            const float vx = acc[r][2] - mx2, vy = acc[r][3] - my2;
            const float vxy = acc[r][4] - mxy;
            const float cv = __fdividef(fmaf(2.f, vxy, 9e-4f), (vx + vy) + 9e-4f);
            if (NEED_L) {
                const float lv = __fdividef(fmaf(2.f, mxy, 1e-4f), (mx2 + my2) + 1e-4f);
                sum_f += lv * cv;
            } else {
                sum_f += cv;
            }
        }
    }

    double s = wred((double)sum_f);
    if ((tid & 63) == 0) red[tid >> 6] = s;
    __syncthreads();
    if (tid == 0) *slot = red[0] + red[1] + red[2] + red[3];
}

// ---------------- kernel A: pool+L2 blocks then ssim0 blocks ----------------

__global__ __launch_bounds__(256, 4)
void kernelA(const float* __restrict__ X, const float* __restrict__ Y,
             float* __restrict__ x1, float* __restrict__ y1,
             float* __restrict__ x2, float* __restrict__ y2,
             double* __restrict__ pcs0, double* __restrict__ pl2)
{
    __shared__ __align__(16) float pl[5 * 26 * 64];
    __shared__ double red[4];
    const int f = blockIdx.x;
    const int tid = threadIdx.x;

    if (f >= NPOOL) {
        const int g  = f - NPOOL;
        const int bz = g / 176;
        const int r  = g - bz * 176;
        ssim_scale<11, 15, 176, 1008, 1008, false>(
            X, Y, r & 15, r >> 4, bz, pl, red, pcs0 + g);
        return;
    }

    // pool path: one 4x4 superpixel/task -> x1 (2x2), x2 (1), + L2 over 16 px
    constexpr int N2 = 64 * 44 * 252;
    float l2 = 0.f;
    for (int e = f * 256 + tid; e < N2; e += NPOOL * 256) {
        const int c2 = e % 252;
        const int t  = e / 252;
        const int r2 = t % 44;
        const int b  = t / 44;
        const size_t ib = ((size_t)(b * 176 + 4 * r2)) * 1008 + 4 * c2;
        const float4 xa = *(const float4*)(X + ib);
        const float4 xb = *(const float4*)(X + ib + 1008);
        const float4 xc = *(const float4*)(X + ib + 2016);
        const float4 xd = *(const float4*)(X + ib + 3024);
        const float4 ya = *(const float4*)(Y + ib);
        const float4 yb = *(const float4*)(Y + ib + 1008);
        const float4 yc = *(const float4*)(Y + ib + 2016);
        const float4 yd = *(const float4*)(Y + ib + 3024);
        float d;
        d = xa.x - ya.x; l2 = fmaf(d, d, l2);
        d = xa.y - ya.y; l2 = fmaf(d, d, l2);
        d = xa.z - ya.z; l2 = fmaf(d, d, l2);
        d = xa.w - ya.w; l2 = fmaf(d, d, l2);
        d = xb.x - yb.x; l2 = fmaf(d, d, l2);
        d = xb.y - yb.y; l2 = fmaf(d, d, l2);
        d = xb.z - yb.z; l2 = fmaf(d, d, l2);
        d = xb.w - yb.w; l2 = fmaf(d, d, l2);
        d = xc.x - yc.x; l2 = fmaf(d, d, l2);
        d = xc.y - yc.y; l2 = fmaf(d, d, l2);
        d = xc.z - yc.z; l2 = fmaf(d, d, l2);
        d = xc.w - yc.w; l2 = fmaf(d, d, l2);
        d = xd.x - yd.x; l2 = fmaf(d, d, l2);
        d = xd.y - yd.y; l2 = fmaf(d, d, l2);
        d = xd.z - yd.z; l2 = fmaf(d, d, l2);
        d = xd.w - yd.w; l2 = fmaf(d, d, l2);

        const float px00 = 0.25f * ((xa.x + xa.y) + (xb.x + xb.y));
        const float px01 = 0.25f * ((xa.z + xa.w) + (xb.z + xb.w));
        const float px10 = 0.25f * ((xc.x + xc.y) + (xd.x + xd.y));
        const float px11 = 0.25f * ((xc.z + xc.w) + (xd.z + xd.w));
        const float py00 = 0.25f * ((ya.x + ya.y) + (yb.x + yb.y));
        const float py01 = 0.25f * ((ya.z + ya.w) + (yb.z + yb.w));
        const float py10 = 0.25f * ((yc.x + yc.y) + (yd.x + yd.y));
        const float py11 = 0.25f * ((yc.z + yc.w) + (yd.z + yd.w));
        const size_t o1 = ((size_t)(b * 88 + 2 * r2)) * 504 + 2 * c2;
        *(float2*)(x1 + o1)       = make_float2(px00, px01);
        *(float2*)(x1 + o1 + 504) = make_float2(px10, px11);
        *(float2*)(y1 + o1)       = make_float2(py00, py01);
        *(float2*)(y1 + o1 + 504) = make_float2(py10, py11);
        const size_t o2 = ((size_t)(b * 44 + r2)) * 252 + c2;
        x2[o2] = 0.25f * ((px00 + px01) + (px10 + px11));
        y2[o2] = 0.25f * ((py00 + py01) + (py10 + py11));
    }
    double s = wred((double)l2);
    if ((tid & 63) == 0) red[tid >> 6] = s;
    __syncthreads();
    if (tid == 0) pl2[f] = red[0] + red[1] + red[2] + red[3];
}

// ---------------- kernel B: ssim1 + ssim2 -----------------------------------

__global__ __launch_bounds__(256, 4)
void kernelB(const float* __restrict__ x1, const float* __restrict__ y1,
             const float* __restrict__ x2, const float* __restrict__ y2,
             double* __restrict__ pcs1, double* __restrict__ plcs2)
{
    __shared__ __align__(16) float pl[5 * 24 * 64];
    __shared__ double red[4];
    const int f = blockIdx.x;
    if (f < NS1) {
        const int bz = f / 48;
        const int r  = f - bz * 48;
        ssim_scale<9, 12, 88, 504, 505, false>(
            x1, y1, r & 7, r >> 3, bz, pl, red, pcs1 + f);
    } else {
        const int g  = f - NS1;
        const int bz = g / 12;
        const int r  = g - bz * 12;
        ssim_scale<7, 10, 44, 252, 253, true>(
            x2, y2, r & 3, r >> 2, bz, pl, red, plcs2 + g);
    }
}

// ---------------- kernel C: final reduce + formula --------------------------

__global__ __launch_bounds__(256)
void kernelC(const double* __restrict__ pcs0, const double* __restrict__ pl2,
             const double* __restrict__ pcs1, const double* __restrict__ plcs2,
             float* __restrict__ out)
{
    const int tid = threadIdx.x;
    double a0 = 0, a1 = 0, a2 = 0, a3 = 0;
    for (int i = tid; i < NS0;   i += 256) a0 += pcs0[i];
    for (int i = tid; i < NPOOL; i += 256) a1 += pl2[i];
    for (int i = tid; i < NS1;   i += 256) a2 += pcs1[i];
    for (int i = tid; i < NS2;   i += 256) a3 += plcs2[i];

    __shared__ double red[4][4];
    double v[4] = {a0, a1, a2, a3};
    const int lane = tid & 63, wv = tid >> 6;
#pragma unroll
    for (int s = 0; s < 4; ++s) {
        const double r = wred(v[s]);
        if (lane == 0) red[s][wv] = r;
    }
    __syncthreads();
    if (tid == 0) {
        double a[4];
#pragma unroll
        for (int s = 0; s < 4; ++s) a[s] = red[s][0] + red[s][1] + red[s][2] + red[s][3];
        const double NE0 = 64.0 * 176.0 * 1008.0;
        const double NE1 = 64.0 * 88.0  * 505.0;
        const double NE2 = 64.0 * 44.0  * 253.0;
        const double cs0 = a[0] / NE0;
        const double l2  = a[1] / NE0;
        const double cs1 = a[2] / NE1;
        const double s2  = a[3] / NE2;
        const double wsum = 0.0448 + 0.2856 + 0.3001;
        const double w0 = 0.0448 / wsum, w1 = 0.2856 / wsum, w2 = 0.3001 / wsum;
        const double ms = pow(cs0, w0) * pow(cs1, w1) * pow(s2, w2);
        const double ssim_loss = 1.0 - ms;
        const double total = 0.3 * l2 + 0.7 * ssim_loss;
        out[0] = (float)total;
        out[1] = (float)l2;
        out[2] = (float)ssim_loss;
    }
}

// ---------------- launch ----------------------------------------------------

extern "C" void kernel_launch(void* const* d_in, const int* in_sizes, int n_in,
                              void* d_out, int out_size, void* d_ws, size_t ws_size,
                              hipStream_t stream)
{
    (void)in_sizes; (void)n_in; (void)out_size; (void)ws_size;

    const float* X = (const float*)d_in[0];
    const float* Y = (const float*)d_in[1];
    float* out = (float*)d_out;

    constexpr int n1 = 64 * 88 * 504;   // 2,838,528
    constexpr int n2 = 64 * 44 * 252;   //   709,632

    double* pcs0  = (double*)d_ws;          // NS0
    double* pl2   = pcs0 + NS0;             // NPOOL
    double* pcs1  = pl2 + NPOOL;            // NS1
    double* plcs2 = pcs1 + NS1;             // NS2
    float* x1 = (float*)(plcs2 + NS2);
    float* y1 = x1 + n1;
    float* x2 = y1 + n1;
    float* y2 = x2 + n2;

    kernelA<<<NPOOL + NS0, 256, 0, stream>>>(X, Y, x1, y1, x2, y2, pcs0, pl2);
    kernelB<<<NS1 + NS2, 256, 0, stream>>>(x1, y1, x2, y2, pcs1, plcs2);
    kernelC<<<1, 256, 0, stream>>>(pcs0, pl2, pcs1, plcs2, out);
}

// Round 8
// 262.865 us; speedup vs baseline: 2.2114x; 2.2114x over previous
//
#include <hip/hip_runtime.h>
#include <math.h>

// ============================================================================
// EnhancedGrayscaleCombinedLoss: 0.3 * L2 + 0.7 * (1 - MS-SSIM(3 scales))
// B=64, C=1, H=176, W=1008 fp32. Out: [total, l2, ssim_loss].
// scale0: win 11x15 pad(5,7) out 176x1008 ; scale1: 9x12 pad(4,6) out 88x505 ;
// scale2: 7x10 pad(3,5) out 44x253. Window separable: outer(gh, gw).
//
// R7 = R2's PROVEN ssim core (126us @scale0, VGPR 52, 0 conflicts, 0 scratch)
//      + 3-kernel fusion (pool+L2+ssim0 / ssim1+ssim2 / final)
//      + fp32 in-thread accumulation, NEED_L specialization.
// The R4/R5 register-window h-pass is abandoned (SROA demoted it to scratch
// twice: 850+ MB spill traffic). No arrays beyond R2's proven acc[4][5]/hv[5].
// ============================================================================

constexpr int NPOOL = 1024;
constexpr int NS0 = 11264;   // 16 x 11 x 64 ssim0 tiles
constexpr int NS1 = 3072;    //  8 x  6 x 64
constexpr int NS2 = 768;     //  4 x  3 x 64

static __device__ __forceinline__ double wred(double v) {
#pragma unroll
    for (int off = 32; off > 0; off >>= 1) v += __shfl_down(v, off, 64);
    return v;
}
static __device__ __forceinline__ float readlane_f(float v, int l) {
    return __int_as_float(__builtin_amdgcn_readlane(__float_as_int(v), l));
}
static __device__ __forceinline__ float firstlane_f(float v) {
    return __int_as_float(__builtin_amdgcn_readfirstlane(__float_as_int(v)));
}

// Normalized 1D gaussian, cooperatively computed, landed in SGPRs.
template <int K>
static __device__ __forceinline__ void gauss_uni(float sigma, float (&g)[K]) {
    const int lane = threadIdx.x & 63;
    const int d = lane - K / 2;
    const float inv2s2 = 1.0f / (2.0f * sigma * sigma);
    float e = (lane < K) ? __expf(-(float)(d * d) * inv2s2) : 0.0f;
    float s = e;
#pragma unroll
    for (int off = 8; off > 0; off >>= 1) s += __shfl_down(s, off, 16);
    const float inv = 1.0f / __shfl(s, 0, 64);
#pragma unroll
    for (int k = 0; k < K; ++k) g[k] = firstlane_f(readlane_f(e, k) * inv);
}

// ---------------- fused separable SSIM, one 16x64 output tile ----------------
// R2 core. NEED_L=false: accumulate cs ; NEED_L=true: accumulate l*cs.

template <int KH, int KW, int H, int W, int Wout, bool NEED_L>
static __device__ void ssim_scale(const float* __restrict__ X,
                                  const float* __restrict__ Y,
                                  int bx, int by, int bz,
                                  float* __restrict__ pl,
                                  double* __restrict__ red,
                                  double* __restrict__ slot)
{
    constexpr int TH = 16, TW = 64;
    constexpr int PADH = KH / 2, PADW = KW / 2;
    constexpr int RH = TH + KH - 1;          // h-rows needed
    constexpr int PS = RH * TW;              // plane stride (floats)

    const int tid = threadIdx.x;
    const int c   = tid & 63;
    const int rg  = tid >> 6;
    const int i0  = by * TH, j0 = bx * TW;
    const float* Xb = X + (size_t)bz * H * W;
    const float* Yb = Y + (size_t)bz * H * W;

    float gh[KH], gw[KW];
    gauss_uni<KH>(1.5f, gh);
    gauss_uni<KW>(1.5f * (float)KW / (float)KH, gw);

    // ---- phase 1: horizontal conv of 5 maps (1 h-point/thread-task) --------
    const bool colsafe = (j0 >= PADW) && (j0 + TW - 1 + (KW - 1 - PADW) < W);
    const int gj0 = j0 - PADW + c;   // global col of window tap 0 for this col
    for (int r = rg; r < RH; r += 4) {
        const int gi = i0 - PADH + r;
        float sx = 0.f, sy = 0.f, sxx = 0.f, syy = 0.f, sxy = 0.f;
        if (gi >= 0 && gi < H) {
            const float* xrow = Xb + (size_t)gi * W + gj0;
            const float* yrow = Yb + (size_t)gi * W + gj0;
            if (colsafe) {
#pragma unroll
                for (int k = 0; k < KW; ++k) {
                    const float xv = xrow[k], yv = yrow[k];
                    const float gx = gw[k] * xv, gy = gw[k] * yv;
                    sx += gx; sy += gy;
                    sxx = fmaf(gx, xv, sxx);
                    syy = fmaf(gy, yv, syy);
                    sxy = fmaf(gx, yv, sxy);
                }
            } else {
#pragma unroll
                for (int k = 0; k < KW; ++k) {
                    float xv = 0.f, yv = 0.f;
                    if ((unsigned)(gj0 + k) < (unsigned)W) { xv = xrow[k]; yv = yrow[k]; }
                    const float gx = gw[k] * xv, gy = gw[k] * yv;
                    sx += gx; sy += gy;
                    sxx = fmaf(gx, xv, sxx);
                    syy = fmaf(gy, yv, syy);
                    sxy = fmaf(gx, yv, sxy);
                }
            }
        }
        float* base = pl + r * TW + c;
        base[0 * PS] = sx;
        base[1 * PS] = sy;
        base[2 * PS] = sxx;
        base[3 * PS] = syy;
        base[4 * PS] = sxy;
    }
    __syncthreads();

    // ---- phase 2: vertical conv (4 rows/thread, sliding) + SSIM ------------
    float acc[4][5];
#pragma unroll
    for (int r = 0; r < 4; ++r)
#pragma unroll
        for (int m = 0; m < 5; ++m) acc[r][m] = 0.f;

    const float* plc = pl + 4 * rg * TW + c;
#pragma unroll
    for (int j = 0; j < KH + 3; ++j) {
        float hv[5];
#pragma unroll
        for (int m = 0; m < 5; ++m) hv[m] = plc[m * PS + j * TW];
#pragma unroll
        for (int r = 0; r < 4; ++r) {
            const int kk = j - r;
            if (kk >= 0 && kk < KH) {
#pragma unroll
                for (int m = 0; m < 5; ++m)
                    acc[r][m] = fmaf(gh[kk], hv[m], acc[r][m]);
            }
        }
    }

    float sum_f = 0.f;
    const int gj  = j0 + c;
    const int gi0 = i0 + 4 * rg;
#pragma unroll
    for (int r = 0; r < 4; ++r) {
        if (gi0 + r < H && gj < Wout) {
            const float mxv = acc[r][0], myv = acc[r][1];
            const float mx2 = mxv * mxv, my2 = myv * myv, mxy = mxv * myv;
            const float vx = acc[r][2] - mx2, vy = acc[r][3] - my2;
            const float vxy = acc[r][4] - mxy;
            const float cv = __fdividef(fmaf(2.f, vxy, 9e-4f), (vx + vy) + 9e-4f);
            if (NEED_L) {
                const float lv = __fdividef(fmaf(2.f, mxy, 1e-4f), (mx2 + my2) + 1e-4f);
                sum_f += lv * cv;
            } else {
                sum_f += cv;
            }
        }
    }

    double s = wred((double)sum_f);
    if ((tid & 63) == 0) red[tid >> 6] = s;
    __syncthreads();
    if (tid == 0) *slot = red[0] + red[1] + red[2] + red[3];
}

// ---------------- kernel A: pool+L2 blocks then ssim0 blocks ----------------

__global__ __launch_bounds__(256)
void kernelA(const float* __restrict__ X, const float* __restrict__ Y,
             float* __restrict__ x1, float* __restrict__ y1,
             float* __restrict__ x2, float* __restrict__ y2,
             double* __restrict__ pcs0, double* __restrict__ pl2)
{
    __shared__ __align__(16) float pl[5 * 26 * 64];
    __shared__ double red[4];
    const int f = blockIdx.x;
    const int tid = threadIdx.x;

    if (f >= NPOOL) {
        const int g  = f - NPOOL;
        const int bz = g / 176;
        const int r  = g - bz * 176;
        ssim_scale<11, 15, 176, 1008, 1008, false>(
            X, Y, r & 15, r >> 4, bz, pl, red, pcs0 + g);
        return;
    }

    // pool path: one 4x4 superpixel/task -> x1 (2x2), x2 (1), + L2 over 16 px
    constexpr int N2 = 64 * 44 * 252;
    float l2 = 0.f;
    for (int e = f * 256 + tid; e < N2; e += NPOOL * 256) {
        const int c2 = e % 252;
        const int t  = e / 252;
        const int r2 = t % 44;
        const int b  = t / 44;
        const size_t ib = ((size_t)(b * 176 + 4 * r2)) * 1008 + 4 * c2;
        const float4 xa = *(const float4*)(X + ib);
        const float4 xb = *(const float4*)(X + ib + 1008);
        const float4 xc = *(const float4*)(X + ib + 2016);
        const float4 xd = *(const float4*)(X + ib + 3024);
        const float4 ya = *(const float4*)(Y + ib);
        const float4 yb = *(const float4*)(Y + ib + 1008);
        const float4 yc = *(const float4*)(Y + ib + 2016);
        const float4 yd = *(const float4*)(Y + ib + 3024);
        float d;
        d = xa.x - ya.x; l2 = fmaf(d, d, l2);
        d = xa.y - ya.y; l2 = fmaf(d, d, l2);
        d = xa.z - ya.z; l2 = fmaf(d, d, l2);
        d = xa.w - ya.w; l2 = fmaf(d, d, l2);
        d = xb.x - yb.x; l2 = fmaf(d, d, l2);
        d = xb.y - yb.y; l2 = fmaf(d, d, l2);
        d = xb.z - yb.z; l2 = fmaf(d, d, l2);
        d = xb.w - yb.w; l2 = fmaf(d, d, l2);
        d = xc.x - yc.x; l2 = fmaf(d, d, l2);
        d = xc.y - yc.y; l2 = fmaf(d, d, l2);
        d = xc.z - yc.z; l2 = fmaf(d, d, l2);
        d = xc.w - yc.w; l2 = fmaf(d, d, l2);
        d = xd.x - yd.x; l2 = fmaf(d, d, l2);
        d = xd.y - yd.y; l2 = fmaf(d, d, l2);
        d = xd.z - yd.z; l2 = fmaf(d, d, l2);
        d = xd.w - yd.w; l2 = fmaf(d, d, l2);

        const float px00 = 0.25f * ((xa.x + xa.y) + (xb.x + xb.y));
        const float px01 = 0.25f * ((xa.z + xa.w) + (xb.z + xb.w));
        const float px10 = 0.25f * ((xc.x + xc.y) + (xd.x + xd.y));
        const float px11 = 0.25f * ((xc.z + xc.w) + (xd.z + xd.w));
        const float py00 = 0.25f * ((ya.x + ya.y) + (yb.x + yb.y));
        const float py01 = 0.25f * ((ya.z + ya.w) + (yb.z + yb.w));
        const float py10 = 0.25f * ((yc.x + yc.y) + (yd.x + yd.y));
        const float py11 = 0.25f * ((yc.z + yc.w) + (yd.z + yd.w));
        const size_t o1 = ((size_t)(b * 88 + 2 * r2)) * 504 + 2 * c2;
        *(float2*)(x1 + o1)       = make_float2(px00, px01);
        *(float2*)(x1 + o1 + 504) = make_float2(px10, px11);
        *(float2*)(y1 + o1)       = make_float2(py00, py01);
        *(float2*)(y1 + o1 + 504) = make_float2(py10, py11);
        const size_t o2 = ((size_t)(b * 44 + r2)) * 252 + c2;
        x2[o2] = 0.25f * ((px00 + px01) + (px10 + px11));
        y2[o2] = 0.25f * ((py00 + py01) + (py10 + py11));
    }
    double s = wred((double)l2);
    if ((tid & 63) == 0) red[tid >> 6] = s;
    __syncthreads();
    if (tid == 0) pl2[f] = red[0] + red[1] + red[2] + red[3];
}

// ---------------- kernel B: ssim1 + ssim2 -----------------------------------

__global__ __launch_bounds__(256)
void kernelB(const float* __restrict__ x1, const float* __restrict__ y1,
             const float* __restrict__ x2, const float* __restrict__ y2,
             double* __restrict__ pcs1, double* __restrict__ plcs2)
{
    __shared__ __align__(16) float pl[5 * 24 * 64];
    __shared__ double red[4];
    const int f = blockIdx.x;
    if (f < NS1) {
        const int bz = f / 48;
        const int r  = f - bz * 48;
        ssim_scale<9, 12, 88, 504, 505, false>(
            x1, y1, r & 7, r >> 3, bz, pl, red, pcs1 + f);
    } else {
        const int g  = f - NS1;
        const int bz = g / 12;
        const int r  = g - bz * 12;
        ssim_scale<7, 10, 44, 252, 253, true>(
            x2, y2, r & 3, r >> 2, bz, pl, red, plcs2 + g);
    }
}

// ---------------- kernel C: final reduce + formula --------------------------

__global__ __launch_bounds__(256)
void kernelC(const double* __restrict__ pcs0, const double* __restrict__ pl2,
             const double* __restrict__ pcs1, const double* __restrict__ plcs2,
             float* __restrict__ out)
{
    const int tid = threadIdx.x;
    double a0 = 0, a1 = 0, a2 = 0, a3 = 0;
    for (int i = tid; i < NS0;   i += 256) a0 += pcs0[i];
    for (int i = tid; i < NPOOL; i += 256) a1 += pl2[i];
    for (int i = tid; i < NS1;   i += 256) a2 += pcs1[i];
    for (int i = tid; i < NS2;   i += 256) a3 += plcs2[i];

    __shared__ double red[4][4];
    double v[4] = {a0, a1, a2, a3};
    const int lane = tid & 63, wv = tid >> 6;
#pragma unroll
    for (int s = 0; s < 4; ++s) {
        const double r = wred(v[s]);
        if (lane == 0) red[s][wv] = r;
    }
    __syncthreads();
    if (tid == 0) {
        double a[4];
#pragma unroll
        for (int s = 0; s < 4; ++s) a[s] = red[s][0] + red[s][1] + red[s][2] + red[s][3];
        const double NE0 = 64.0 * 176.0 * 1008.0;
        const double NE1 = 64.0 * 88.0  * 505.0;
        const double NE2 = 64.0 * 44.0  * 253.0;
        const double cs0 = a[0] / NE0;
        const double l2  = a[1] / NE0;
        const double cs1 = a[2] / NE1;
        const double s2  = a[3] / NE2;
        const double wsum = 0.0448 + 0.2856 + 0.3001;
        const double w0 = 0.0448 / wsum, w1 = 0.2856 / wsum, w2 = 0.3001 / wsum;
        const double ms = pow(cs0, w0) * pow(cs1, w1) * pow(s2, w2);
        const double ssim_loss = 1.0 - ms;
        const double total = 0.3 * l2 + 0.7 * ssim_loss;
        out[0] = (float)total;
        out[1] = (float)l2;
        out[2] = (float)ssim_loss;
    }
}

// ---------------- launch ----------------------------------------------------

extern "C" void kernel_launch(void* const* d_in, const int* in_sizes, int n_in,
                              void* d_out, int out_size, void* d_ws, size_t ws_size,
                              hipStream_t stream)
{
    (void)in_sizes; (void)n_in; (void)out_size; (void)ws_size;

    const float* X = (const float*)d_in[0];
    const float* Y = (const float*)d_in[1];
    float* out = (float*)d_out;

    constexpr int n1 = 64 * 88 * 504;   // 2,838,528
    constexpr int n2 = 64 * 44 * 252;   //   709,632

    double* pcs0  = (double*)d_ws;          // NS0
    double* pl2   = pcs0 + NS0;             // NPOOL
    double* pcs1  = pl2 + NPOOL;            // NS1
    double* plcs2 = pcs1 + NS1;             // NS2
    float* x1 = (float*)(plcs2 + NS2);
    float* y1 = x1 + n1;
    float* x2 = y1 + n1;
    float* y2 = x2 + n2;

    kernelA<<<NPOOL + NS0, 256, 0, stream>>>(X, Y, x1, y1, x2, y2, pcs0, pl2);
    kernelB<<<NS1 + NS2, 256, 0, stream>>>(x1, y1, x2, y2, pcs1, plcs2);
    kernelC<<<1, 256, 0, stream>>>(pcs0, pl2, pcs1, plcs2, out);
}

// Round 9
// 254.185 us; speedup vs baseline: 2.2869x; 1.0342x over previous
//
#include <hip/hip_runtime.h>
#include <math.h>

// ============================================================================
// EnhancedGrayscaleCombinedLoss: 0.3 * L2 + 0.7 * (1 - MS-SSIM(3 scales))
// B=64, C=1, H=176, W=1008 fp32. Out: [total, l2, ssim_loss].
// scale0: win 11x15 pad(5,7) out 176x1008 ; scale1: 9x12 pad(4,6) out 88x505 ;
// scale2: 7x10 pad(3,5) out 44x253. Window separable: outer(gh, gw).
//
// R9 = R8 (proven: 143us kernelA, VGPR 52, 0 scratch, 0 conflicts) with the
// x/y symmetric streams paired into float2 ext-vectors so the backend can
// emit v_pk_{mul,add,fma}_f32 (full-rate packed fp32, CDNA):
//   h-tap: 7 VALU -> 4 (pk_mul + pk_add + pk_fma + scalar fma)
//   v-tap: 5 VALU + 5 ds_read_b32 -> 3 VALU + 2 ds_read_b64 + 1 ds_read_b32
// LDS planes interleaved as (hx,hy),(hxx,hyy),hxy. Same sizes, same structure.
// ============================================================================

constexpr int NPOOL = 1024;
constexpr int NS0 = 11264;   // 16 x 11 x 64 ssim0 tiles
constexpr int NS1 = 3072;    //  8 x  6 x 64
constexpr int NS2 = 768;     //  4 x  3 x 64

typedef float f2 __attribute__((ext_vector_type(2)));

static __device__ __forceinline__ double wred(double v) {
#pragma unroll
    for (int off = 32; off > 0; off >>= 1) v += __shfl_down(v, off, 64);
    return v;
}
static __device__ __forceinline__ float readlane_f(float v, int l) {
    return __int_as_float(__builtin_amdgcn_readlane(__float_as_int(v), l));
}
static __device__ __forceinline__ float firstlane_f(float v) {
    return __int_as_float(__builtin_amdgcn_readfirstlane(__float_as_int(v)));
}

// Normalized 1D gaussian, cooperatively computed, landed in SGPRs.
template <int K>
static __device__ __forceinline__ void gauss_uni(float sigma, float (&g)[K]) {
    const int lane = threadIdx.x & 63;
    const int d = lane - K / 2;
    const float inv2s2 = 1.0f / (2.0f * sigma * sigma);
    float e = (lane < K) ? __expf(-(float)(d * d) * inv2s2) : 0.0f;
    float s = e;
#pragma unroll
    for (int off = 8; off > 0; off >>= 1) s += __shfl_down(s, off, 16);
    const float inv = 1.0f / __shfl(s, 0, 64);
#pragma unroll
    for (int k = 0; k < K; ++k) g[k] = firstlane_f(readlane_f(e, k) * inv);
}

// ---------------- fused separable SSIM, one 16x64 output tile ----------------
// NEED_L=false: accumulate cs ; NEED_L=true: accumulate l*cs. One slot/block.

template <int KH, int KW, int H, int W, int Wout, bool NEED_L>
static __device__ void ssim_scale(const float* __restrict__ X,
                                  const float* __restrict__ Y,
                                  int bx, int by, int bz,
                                  float* __restrict__ pl,
                                  double* __restrict__ red,
                                  double* __restrict__ slot)
{
    constexpr int TH = 16, TW = 64;
    constexpr int PADH = KH / 2, PADW = KW / 2;
    constexpr int RH = TH + KH - 1;          // h-rows needed
    constexpr int NPX = RH * TW;             // pixels per plane

    const int tid = threadIdx.x;
    const int c   = tid & 63;
    const int rg  = tid >> 6;
    const int i0  = by * TH, j0 = bx * TW;
    const float* Xb = X + (size_t)bz * H * W;
    const float* Yb = Y + (size_t)bz * H * W;

    f2* pl01 = (f2*)pl;                      // (sx,sy) pairs    [NPX]
    f2* pl23 = (f2*)(pl + 2 * NPX);          // (sxx,syy) pairs  [NPX]
    float* pl4 = pl + 4 * NPX;               // sxy scalars      [NPX]

    float gh[KH], gw[KW];
    gauss_uni<KH>(1.5f, gh);
    gauss_uni<KW>(1.5f * (float)KW / (float)KH, gw);

    // ---- phase 1: horizontal conv of 5 maps (1 h-point/thread-task) --------
    const bool colsafe = (j0 >= PADW) && (j0 + TW - 1 + (KW - 1 - PADW) < W);
    const int gj0 = j0 - PADW + c;   // global col of window tap 0 for this col
    for (int r = rg; r < RH; r += 4) {
        const int gi = i0 - PADH + r;
        f2 s01 = {0.f, 0.f};
        f2 s23 = {0.f, 0.f};
        float s4 = 0.f;
        if (gi >= 0 && gi < H) {
            const float* xrow = Xb + (size_t)gi * W + gj0;
            const float* yrow = Yb + (size_t)gi * W + gj0;
            if (colsafe) {
#pragma unroll
                for (int k = 0; k < KW; ++k) {
                    const float xv = xrow[k], yv = yrow[k];
                    const f2 p = {xv, yv};
                    const f2 gp = gw[k] * p;                       // pk_mul
                    s01 += gp;                                     // pk_add
                    s23 = __builtin_elementwise_fma(gp, p, s23);   // pk_fma
                    s4  = fmaf(gp.x, yv, s4);                      // fma
                }
            } else {
#pragma unroll
                for (int k = 0; k < KW; ++k) {
                    float xv = 0.f, yv = 0.f;
                    if ((unsigned)(gj0 + k) < (unsigned)W) { xv = xrow[k]; yv = yrow[k]; }
                    const f2 p = {xv, yv};
                    const f2 gp = gw[k] * p;
                    s01 += gp;
                    s23 = __builtin_elementwise_fma(gp, p, s23);
                    s4  = fmaf(gp.x, yv, s4);
                }
            }
        }
        const int px = r * TW + c;
        pl01[px] = s01;
        pl23[px] = s23;
        pl4 [px] = s4;
    }
    __syncthreads();

    // ---- phase 2: vertical conv (4 rows/thread, sliding) + SSIM ------------
    f2 a01[4], a23[4];
    float a4[4];
#pragma unroll
    for (int r = 0; r < 4; ++r) {
        a01[r] = (f2){0.f, 0.f};
        a23[r] = (f2){0.f, 0.f};
        a4[r] = 0.f;
    }

    const int baserow = 4 * rg;
#pragma unroll
    for (int j = 0; j < KH + 3; ++j) {
        const int px = (baserow + j) * TW + c;
        const f2 h01 = pl01[px];                 // ds_read_b64
        const f2 h23 = pl23[px];                 // ds_read_b64
        const float h4 = pl4[px];                // ds_read_b32
#pragma unroll
        for (int r = 0; r < 4; ++r) {
            const int kk = j - r;
            if (kk >= 0 && kk < KH) {
                const f2 g2 = {gh[kk], gh[kk]};
                a01[r] = __builtin_elementwise_fma(g2, h01, a01[r]);  // pk_fma
                a23[r] = __builtin_elementwise_fma(g2, h23, a23[r]);  // pk_fma
                a4[r]  = fmaf(gh[kk], h4, a4[r]);                     // fma
            }
        }
    }

    float sum_f = 0.f;
    const int gj  = j0 + c;
    const int gi0 = i0 + 4 * rg;
#pragma unroll
    for (int r = 0; r < 4; ++r) {
        if (gi0 + r < H && gj < Wout) {
            const float mxv = a01[r].x, myv = a01[r].y;
            const float mx2 = mxv * mxv, my2 = myv * myv, mxy = mxv * myv;
            const float vx = a23[r].x - mx2, vy = a23[r].y - my2;
            const float vxy = a4[r] - mxy;
            const float cv = __fdividef(fmaf(2.f, vxy, 9e-4f), (vx + vy) + 9e-4f);
            if (NEED_L) {
                const float lv = __fdividef(fmaf(2.f, mxy, 1e-4f), (mx2 + my2) + 1e-4f);
                sum_f += lv * cv;
            } else {
                sum_f += cv;
            }
        }
    }

    double s = wred((double)sum_f);
    if ((tid & 63) == 0) red[tid >> 6] = s;
    __syncthreads();
    if (tid == 0) *slot = red[0] + red[1] + red[2] + red[3];
}

// ---------------- kernel A: pool+L2 blocks then ssim0 blocks ----------------

__global__ __launch_bounds__(256)
void kernelA(const float* __restrict__ X, const float* __restrict__ Y,
             float* __restrict__ x1, float* __restrict__ y1,
             float* __restrict__ x2, float* __restrict__ y2,
             double* __restrict__ pcs0, double* __restrict__ pl2)
{
    __shared__ __align__(16) float pl[5 * 26 * 64];
    __shared__ double red[4];
    const int f = blockIdx.x;
    const int tid = threadIdx.x;

    if (f >= NPOOL) {
        const int g  = f - NPOOL;
        const int bz = g / 176;
        const int r  = g - bz * 176;
        ssim_scale<11, 15, 176, 1008, 1008, false>(
            X, Y, r & 15, r >> 4, bz, pl, red, pcs0 + g);
        return;
    }

    // pool path: one 4x4 superpixel/task -> x1 (2x2), x2 (1), + L2 over 16 px
    constexpr int N2 = 64 * 44 * 252;
    float l2 = 0.f;
    for (int e = f * 256 + tid; e < N2; e += NPOOL * 256) {
        const int c2 = e % 252;
        const int t  = e / 252;
        const int r2 = t % 44;
        const int b  = t / 44;
        const size_t ib = ((size_t)(b * 176 + 4 * r2)) * 1008 + 4 * c2;
        const float4 xa = *(const float4*)(X + ib);
        const float4 xb = *(const float4*)(X + ib + 1008);
        const float4 xc = *(const float4*)(X + ib + 2016);
        const float4 xd = *(const float4*)(X + ib + 3024);
        const float4 ya = *(const float4*)(Y + ib);
        const float4 yb = *(const float4*)(Y + ib + 1008);
        const float4 yc = *(const float4*)(Y + ib + 2016);
        const float4 yd = *(const float4*)(Y + ib + 3024);
        float d;
        d = xa.x - ya.x; l2 = fmaf(d, d, l2);
        d = xa.y - ya.y; l2 = fmaf(d, d, l2);
        d = xa.z - ya.z; l2 = fmaf(d, d, l2);
        d = xa.w - ya.w; l2 = fmaf(d, d, l2);
        d = xb.x - yb.x; l2 = fmaf(d, d, l2);
        d = xb.y - yb.y; l2 = fmaf(d, d, l2);
        d = xb.z - yb.z; l2 = fmaf(d, d, l2);
        d = xb.w - yb.w; l2 = fmaf(d, d, l2);
        d = xc.x - yc.x; l2 = fmaf(d, d, l2);
        d = xc.y - yc.y; l2 = fmaf(d, d, l2);
        d = xc.z - yc.z; l2 = fmaf(d, d, l2);
        d = xc.w - yc.w; l2 = fmaf(d, d, l2);
        d = xd.x - yd.x; l2 = fmaf(d, d, l2);
        d = xd.y - yd.y; l2 = fmaf(d, d, l2);
        d = xd.z - yd.z; l2 = fmaf(d, d, l2);
        d = xd.w - yd.w; l2 = fmaf(d, d, l2);

        const float px00 = 0.25f * ((xa.x + xa.y) + (xb.x + xb.y));
        const float px01 = 0.25f * ((xa.z + xa.w) + (xb.z + xb.w));
        const float px10 = 0.25f * ((xc.x + xc.y) + (xd.x + xd.y));
        const float px11 = 0.25f * ((xc.z + xc.w) + (xd.z + xd.w));
        const float py00 = 0.25f * ((ya.x + ya.y) + (yb.x + yb.y));
        const float py01 = 0.25f * ((ya.z + ya.w) + (yb.z + yb.w));
        const float py10 = 0.25f * ((yc.x + yc.y) + (yd.x + yd.y));
        const float py11 = 0.25f * ((yc.z + yc.w) + (yd.z + yd.w));
        const size_t o1 = ((size_t)(b * 88 + 2 * r2)) * 504 + 2 * c2;
        *(float2*)(x1 + o1)       = make_float2(px00, px01);
        *(float2*)(x1 + o1 + 504) = make_float2(px10, px11);
        *(float2*)(y1 + o1)       = make_float2(py00, py01);
        *(float2*)(y1 + o1 + 504) = make_float2(py10, py11);
        const size_t o2 = ((size_t)(b * 44 + r2)) * 252 + c2;
        x2[o2] = 0.25f * ((px00 + px01) + (px10 + px11));
        y2[o2] = 0.25f * ((py00 + py01) + (py10 + py11));
    }
    double s = wred((double)l2);
    if ((tid & 63) == 0) red[tid >> 6] = s;
    __syncthreads();
    if (tid == 0) pl2[f] = red[0] + red[1] + red[2] + red[3];
}

// ---------------- kernel B: ssim1 + ssim2 -----------------------------------

__global__ __launch_bounds__(256)
void kernelB(const float* __restrict__ x1, const float* __restrict__ y1,
             const float* __restrict__ x2, const float* __restrict__ y2,
             double* __restrict__ pcs1, double* __restrict__ plcs2)
{
    __shared__ __align__(16) float pl[5 * 24 * 64];
    __shared__ double red[4];
    const int f = blockIdx.x;
    if (f < NS1) {
        const int bz = f / 48;
        const int r  = f - bz * 48;
        ssim_scale<9, 12, 88, 504, 505, false>(
            x1, y1, r & 7, r >> 3, bz, pl, red, pcs1 + f);
    } else {
        const int g  = f - NS1;
        const int bz = g / 12;
        const int r  = g - bz * 12;
        ssim_scale<7, 10, 44, 252, 253, true>(
            x2, y2, r & 3, r >> 2, bz, pl, red, plcs2 + g);
    }
}

// ---------------- kernel C: final reduce + formula --------------------------

__global__ __launch_bounds__(256)
void kernelC(const double* __restrict__ pcs0, const double* __restrict__ pl2,
             const double* __restrict__ pcs1, const double* __restrict__ plcs2,
             float* __restrict__ out)
{
    const int tid = threadIdx.x;
    double a0 = 0, a1 = 0, a2 = 0, a3 = 0;
    for (int i = tid; i < NS0;   i += 256) a0 += pcs0[i];
    for (int i = tid; i < NPOOL; i += 256) a1 += pl2[i];
    for (int i = tid; i < NS1;   i += 256) a2 += pcs1[i];
    for (int i = tid; i < NS2;   i += 256) a3 += plcs2[i];

    __shared__ double red[4][4];
    double v[4] = {a0, a1, a2, a3};
    const int lane = tid & 63, wv = tid >> 6;
#pragma unroll
    for (int s = 0; s < 4; ++s) {
        const double r = wred(v[s]);
        if (lane == 0) red[s][wv] = r;
    }
    __syncthreads();
    if (tid == 0) {
        double a[4];
#pragma unroll
        for (int s = 0; s < 4; ++s) a[s] = red[s][0] + red[s][1] + red[s][2] + red[s][3];
        const double NE0 = 64.0 * 176.0 * 1008.0;
        const double NE1 = 64.0 * 88.0  * 505.0;
        const double NE2 = 64.0 * 44.0  * 253.0;
        const double cs0 = a[0] / NE0;
        const double l2  = a[1] / NE0;
        const double cs1 = a[2] / NE1;
        const double s2  = a[3] / NE2;
        const double wsum = 0.0448 + 0.2856 + 0.3001;
        const double w0 = 0.0448 / wsum, w1 = 0.2856 / wsum, w2 = 0.3001 / wsum;
        const double ms = pow(cs0, w0) * pow(cs1, w1) * pow(s2, w2);
        const double ssim_loss = 1.0 - ms;
        const double total = 0.3 * l2 + 0.7 * ssim_loss;
        out[0] = (float)total;
        out[1] = (float)l2;
        out[2] = (float)ssim_loss;
    }
}

// ---------------- launch ----------------------------------------------------

extern "C" void kernel_launch(void* const* d_in, const int* in_sizes, int n_in,
                              void* d_out, int out_size, void* d_ws, size_t ws_size,
                              hipStream_t stream)
{
    (void)in_sizes; (void)n_in; (void)out_size; (void)ws_size;

    const float* X = (const float*)d_in[0];
    const float* Y = (const float*)d_in[1];
    float* out = (float*)d_out;

    constexpr int n1 = 64 * 88 * 504;   // 2,838,528
    constexpr int n2 = 64 * 44 * 252;   //   709,632

    double* pcs0  = (double*)d_ws;          // NS0
    double* pl2   = pcs0 + NS0;             // NPOOL
    double* pcs1  = pl2 + NPOOL;            // NS1
    double* plcs2 = pcs1 + NS1;             // NS2
    float* x1 = (float*)(plcs2 + NS2);
    float* y1 = x1 + n1;
    float* x2 = y1 + n1;
    float* y2 = x2 + n2;

    kernelA<<<NPOOL + NS0, 256, 0, stream>>>(X, Y, x1, y1, x2, y2, pcs0, pl2);
    kernelB<<<NS1 + NS2, 256, 0, stream>>>(x1, y1, x2, y2, pcs1, plcs2);
    kernelC<<<1, 256, 0, stream>>>(pcs0, pl2, pcs1, plcs2, out);
}